// Round 2
// baseline (239.729 us; speedup 1.0000x reference)
//
#include <hip/hip_runtime.h>
#include <hip/hip_bf16.h>

// GQA prefill: x@[Wq|Wk|Wv] (rope fused) -> causal GQA flash attention -> @Wo
// B=2 S=2048 D=2048 H=32 Hkv=8 hd=64 G=4. All GEMMs bf16-MFMA, fp32 accum.
// R2: fat-wave attention. 32 q-rows per wave (2 col-tiles), 128-row q-supertile
// per block, supertiles mirror-paired (i,15-i) -> 34 balanced iterations.
// K/V fragments loaded once per tile feed 32 MFMAs (was 16): LDS traffic and
// barrier count per MFMA ~halved. 512 blocks, 2/CU, 8 waves/CU (AITER regime).

#define S_LEN 2048
#define DIM   2048
#define NH    32
#define NKV   8
#define HD    64
#define BS    4096      // B*S rows
#define NQKV  3072      // 2048 q + 512 k + 512 v
#define LL(x) ((long long)(x))

typedef __bf16 bf16x8 __attribute__((ext_vector_type(8)));
typedef float  f32x4  __attribute__((ext_vector_type(4)));

__device__ __forceinline__ unsigned short bfb(float f) {
  __hip_bfloat16 h = __float2bfloat16(f);
  return *reinterpret_cast<unsigned short*>(&h);
}

__device__ __forceinline__ unsigned cvtpk(float lo, float hi) {
  unsigned u;
  asm("v_cvt_pk_bf16_f32 %0, %1, %2" : "=v"(u) : "v"(lo), "v"(hi));
  return u;
}

__device__ __forceinline__ void gload16(const void* g, void* l) {
  __builtin_amdgcn_global_load_lds(
      (const __attribute__((address_space(1))) void*)g,
      (__attribute__((address_space(3))) void*)l, 16, 0, 0);
}

// ---- RoPE cos/sin table: [2048][32][2] f32 (double trig for accuracy) ----
__global__ void k_rope_tab(float* __restrict__ tab) {
  int i = blockIdx.x * 256 + threadIdx.x;
  if (i >= S_LEN * 32) return;
  int s = i >> 5, f = i & 31;
  double inv = pow(500000.0, -2.0 * (double)f / 64.0);
  double fr = (double)s * inv;
  tab[2 * i]     = (float)cos(fr);
  tab[2 * i + 1] = (float)sin(fr);
}

// ---- fp32 -> bf16 cast, 4-wide ----
__global__ void k_cast4(const float* __restrict__ in, unsigned short* __restrict__ out, int n4) {
  int i = blockIdx.x * 256 + threadIdx.x;
  if (i >= n4) return;
  float4 v = ((const float4*)in)[i];
  ushort4 o;
  o.x = bfb(v.x); o.y = bfb(v.y); o.z = bfb(v.z); o.w = bfb(v.w);
  ((ushort4*)out)[i] = o;
}

// ---- transpose + cast: in[K][N] f32 -> out[N][K] bf16 ----
__global__ void k_tcast(const float* __restrict__ in, unsigned short* __restrict__ out,
                        int K, int N) {
  __shared__ float tile[32][33];
  int n0 = blockIdx.x * 32, k0 = blockIdx.y * 32;
  int tx = threadIdx.x, ty = threadIdx.y;  // 32x8
#pragma unroll
  for (int r = 0; r < 32; r += 8) tile[ty + r][tx] = in[LL(k0 + ty + r) * N + n0 + tx];
  __syncthreads();
#pragma unroll
  for (int r = 0; r < 32; r += 8) out[LL(n0 + ty + r) * K + k0 + tx] = bfb(tile[tx][ty + r]);
}

// ---- V transpose: vbuf[(b*S+s)][kvh*64+d] -> vt[(b*8+kvh)*64+d][s] (bf16) ----
__global__ void k_vtrans(const unsigned short* __restrict__ vbuf, unsigned short* __restrict__ vt) {
  __shared__ __align__(16) unsigned short tile[64][72];
  int s0 = blockIdx.x * 64;
  int bh = blockIdx.y;             // b*8 + kvh
  int b = bh >> 3, kvh = bh & 7;
  int t = threadIdx.x;
#pragma unroll
  for (int c = t; c < 512; c += 256) {
    int s = c >> 3, seg = c & 7;
    *(uint4*)&tile[s][seg * 8] =
        *(const uint4*)(vbuf + LL(b * S_LEN + s0 + s) * (NKV * HD) + kvh * HD + seg * 8);
  }
  __syncthreads();
#pragma unroll
  for (int c = t; c < 512; c += 256) {
    int d = c >> 3, sseg = c & 7;
    ushort4 x0, x1;
    unsigned short* xp = (unsigned short*)&x0;
#pragma unroll
    for (int j = 0; j < 4; j++) xp[j] = tile[sseg * 8 + j][d];
    unsigned short* yp = (unsigned short*)&x1;
#pragma unroll
    for (int j = 0; j < 4; j++) yp[j] = tile[sseg * 8 + 4 + j][d];
    uint4 o;
    o.x = ((unsigned*)&x0)[0]; o.y = ((unsigned*)&x0)[1];
    o.z = ((unsigned*)&x1)[0]; o.w = ((unsigned*)&x1)[1];
    *(uint4*)(vt + (LL(bh) * HD + d) * S_LEN + s0 + sseg * 8) = o;
  }
}

// ---- bf16 MFMA GEMM: C[M][N] = A[M][K] * Bt[N][K]^T  (m97 structure + T1 swizzle) ----
// MODE 0: fp32 out. MODE 2: fused QKV epilogue (rope on q/k cols, split outputs).
template <int MODE>
__global__ __launch_bounds__(256, 2) void k_gemm(
    const unsigned short* __restrict__ A, const unsigned short* __restrict__ Bt,
    void* __restrict__ Cout, int M, int N, int K,
    const float* __restrict__ tab, unsigned short* __restrict__ qbuf,
    unsigned short* __restrict__ kbuf, unsigned short* __restrict__ vbuf) {
  __shared__ __align__(16) unsigned short As[128 * 32];
  __shared__ __align__(16) unsigned short Bs[128 * 32];
  int t = threadIdx.x;
  int lane = t & 63, w = t >> 6;
  int wr = w >> 1, wc = w & 1;
  int g = lane >> 4, r = lane & 15;
  // XCD-aware bijective swizzle (nwg % 8 == 0 for all our launches)
  int gx = gridDim.x;
  int nwg = gx * gridDim.y;
  int lin = blockIdx.y * gx + blockIdx.x;
  int cpx = nwg >> 3;
  int swz = (lin & 7) * cpx + (lin >> 3);
  int bx = swz % gx, by = swz / gx;
  long long rowBase = LL(by) * 128;
  long long colBase = LL(bx) * 128;

  f32x4 acc[4][4] = {};

  int c0 = t, c1 = t + 256;
  const unsigned short* ag0 = A + (rowBase + (c0 >> 2)) * K + (c0 & 3) * 8;
  const unsigned short* ag1 = A + (rowBase + (c1 >> 2)) * K + (c1 & 3) * 8;
  const unsigned short* bg0 = Bt + (colBase + (c0 >> 2)) * K + (c0 & 3) * 8;
  const unsigned short* bg1 = Bt + (colBase + (c1 >> 2)) * K + (c1 & 3) * 8;
  char* lA0 = (char*)As + c0 * 16; char* lA1 = (char*)As + c1 * 16;
  char* lB0 = (char*)Bs + c0 * 16; char* lB1 = (char*)Bs + c1 * 16;

  for (int kt = 0; kt < K; kt += 32) {
    __syncthreads();
    gload16(ag0 + kt, lA0);
    gload16(ag1 + kt, lA1);
    gload16(bg0 + kt, lB0);
    gload16(bg1 + kt, lB1);
    __syncthreads();

    bf16x8 af[4], bfr[4];
#pragma unroll
    for (int m = 0; m < 4; m++)
      af[m] = *(const bf16x8*)(const void*)(As + (wr * 64 + m * 16 + r) * 32 + g * 8);
#pragma unroll
    for (int n = 0; n < 4; n++)
      bfr[n] = *(const bf16x8*)(const void*)(Bs + (wc * 64 + n * 16 + r) * 32 + g * 8);
#pragma unroll
    for (int m = 0; m < 4; m++)
#pragma unroll
      for (int n = 0; n < 4; n++)
        acc[m][n] = __builtin_amdgcn_mfma_f32_16x16x32_bf16(af[m], bfr[n], acc[m][n], 0, 0, 0);
  }

  if (MODE == 0) {
#pragma unroll
    for (int m = 0; m < 4; m++)
#pragma unroll
      for (int n = 0; n < 4; n++) {
        long long row0 = rowBase + wr * 64 + m * 16 + g * 4;
        long long col = colBase + wc * 64 + n * 16 + r;
#pragma unroll
        for (int j = 0; j < 4; j++)
          ((float*)Cout)[(row0 + j) * N + col] = acc[m][n][j];
      }
  } else {
    // fused QKV epilogue. cols: [0,2048) q (rope, *0.125*log2e), [2048,2560) k (rope),
    // [2560,3072) v (plain). rope: partner value in lane r^1.
#pragma unroll
    for (int n = 0; n < 4; n++) {
      int gc0 = (int)colBase + wc * 64 + n * 16;  // uniform 16-col block
      int gc = gc0 + r;
      unsigned short* dst; int dcol, dstride; float scale; bool rope;
      if (gc0 < 2048)      { dst = qbuf; dcol = gc;        dstride = DIM; scale = 0.18033688f; rope = true; }
      else if (gc0 < 2560) { dst = kbuf; dcol = gc - 2048; dstride = 512; scale = 1.0f;        rope = true; }
      else                 { dst = vbuf; dcol = gc - 2560; dstride = 512; scale = 1.0f;        rope = false; }
      int f = (gc & 63) >> 1;
      float sgn = (gc & 1) ? 1.f : -1.f;
#pragma unroll
      for (int m = 0; m < 4; m++) {
        long long row0 = rowBase + wr * 64 + m * 16 + g * 4;
#pragma unroll
        for (int j = 0; j < 4; j++) {
          float v = acc[m][n][j];
          float o;
          if (rope) {
            float part = __shfl_xor(v, 1);
            int s = (int)((row0 + j) & (S_LEN - 1));
            float cc = tab[(s * 32 + f) * 2], ss = tab[(s * 32 + f) * 2 + 1];
            o = (v * cc + sgn * part * ss) * scale;
          } else o = v;
          dst[(row0 + j) * dstride + dcol] = bfb(o);
        }
      }
    }
  }
}

// ---- causal GQA flash attention, fat waves ----
// grid (8, H, B); block 256 (4 waves x 32 q-rows = 128-row supertile).
// Block runs supertile pair (p, 15-p): 34 balanced KV-tile iterations.
// Per tile: K/V frags read once, feed 2 col-tiles (32 MFMA/wave).
// 48KB LDS, 2 blocks/CU (8 waves/CU). Dbuf K/V via global_load_lds,
// counted vmcnt(4), 2 barriers per tile.
__global__ __launch_bounds__(256, 2) void k_attn(
    const unsigned short* __restrict__ qb, const unsigned short* __restrict__ kb,
    const unsigned short* __restrict__ vt, unsigned short* __restrict__ zb) {
  int pair = blockIdx.x;           // 0..7
  int h = blockIdx.y, b = blockIdx.z;
  int kvh = h >> 2, bh = b * NKV + kvh;
  int t = threadIdx.x, lane = t & 63, w = t >> 6;
  int g = lane >> 4, r = lane & 15;
  int sw = (r & 7) * 8;   // ushort-index XOR swizzle (16B granule on 128B rows)

  __shared__ __align__(16) unsigned short Ks[2][64 * 64];     // [key][d]  swizzled
  __shared__ __align__(16) unsigned short Vs[2][64 * 64];     // [d][key]  swizzled
  __shared__ __align__(16) unsigned short Ps[4][2][16 * 64];  // per-wave/ctile [qrow][key]

  // staging chunks: c -> row=c>>3, slot=c&7; source slot ^= row&7
  int c0 = t, c1 = t + 256;
  const unsigned short* kg0 = kb + LL(b) * S_LEN * 512 + (c0 >> 3) * 512 + kvh * HD
                                 + (((c0 & 7) ^ ((c0 >> 3) & 7)) * 8);
  const unsigned short* kg1 = kb + LL(b) * S_LEN * 512 + (c1 >> 3) * 512 + kvh * HD
                                 + (((c1 & 7) ^ ((c1 >> 3) & 7)) * 8);
  const unsigned short* vg0 = vt + (LL(bh) * HD + (c0 >> 3)) * S_LEN
                                 + (((c0 & 7) ^ ((c0 >> 3) & 7)) * 8);
  const unsigned short* vg1 = vt + (LL(bh) * HD + (c1 >> 3)) * S_LEN
                                 + (((c1 & 7) ^ ((c1 >> 3) & 7)) * 8);

#define STAGE(bufi, kst_)                                              \
  {                                                                    \
    gload16(kg0 + LL(kst_) * 512, (char*)Ks[bufi] + c0 * 16);          \
    gload16(kg1 + LL(kst_) * 512, (char*)Ks[bufi] + c1 * 16);          \
    gload16(vg0 + (kst_), (char*)Vs[bufi] + c0 * 16);                  \
    gload16(vg1 + (kst_), (char*)Vs[bufi] + c1 * 16);                  \
  }

#pragma unroll 1
  for (int pass = 0; pass < 2; pass++) {
    int st = pass ? (15 - pair) : pair;   // supertile index
    int qbase = st * 128;
    int rowb = qbase + w * 32;            // wave's first q-row

    // Q fragments (pre-scaled by 0.125*log2e in GEMM epilogue), 2 col-tiles
    bf16x8 qf[2][2];
#pragma unroll
    for (int c = 0; c < 2; c++) {
      long long qr = LL(b) * S_LEN + rowb + c * 16 + r;
      qf[c][0] = *(const bf16x8*)(const void*)(qb + qr * DIM + h * HD + g * 8);
      qf[c][1] = *(const bf16x8*)(const void*)(qb + qr * DIM + h * HD + 32 + g * 8);
    }

    f32x4 acc[2][4] = {};   // acc[c][d][j] = O^T[d*16+g*4+j][qrow rowb+16c+r]
    float mrun[2] = {-1e30f, -1e30f};
    float lrun[2] = {0.f, 0.f};

    int nt = 2 * st + 2;
    __syncthreads();          // prior pass's readers done; buffers free
    STAGE(0, 0);
    for (int tt = 0; tt < nt; tt++) {
      int kst = tt * 64;
      int cur = tt & 1;
      if (tt + 1 < nt) {
        STAGE(cur ^ 1, kst + 64);
        asm volatile("s_waitcnt vmcnt(4)" ::: "memory");  // tile tt landed
      } else {
        asm volatile("s_waitcnt vmcnt(0)" ::: "memory");
      }
      __builtin_amdgcn_s_barrier();
      __builtin_amdgcn_sched_barrier(0);

      // wave-uniform: does this tile intersect any of this wave's rows?
      if (kst <= rowb + 31) {
        const unsigned short* Kc = Ks[cur];
        const unsigned short* Vc = Vs[cur];

        // K and V fragments: read ONCE, feed both col-tiles (32 MFMA)
        bf16x8 kfr[4][2], vfr[4][2];
#pragma unroll
        for (int nf = 0; nf < 4; nf++)
#pragma unroll
          for (int kd = 0; kd < 2; kd++)
            kfr[nf][kd] = *(const bf16x8*)(const void*)(
                Kc + (nf * 16 + r) * 64 + ((kd * 32 + g * 8) ^ sw));
#pragma unroll
        for (int d = 0; d < 4; d++)
#pragma unroll
          for (int ks = 0; ks < 2; ks++)
            vfr[d][ks] = *(const bf16x8*)(const void*)(
                Vc + (d * 16 + r) * 64 + ((ks * 32 + g * 8) ^ sw));

#pragma unroll
        for (int c = 0; c < 2; c++) {
          unsigned short* Pw = Ps[w][c];
          int qg = rowb + c * 16 + r;

          __builtin_amdgcn_s_setprio(1);
          f32x4 sc[4] = {};
#pragma unroll
          for (int nf = 0; nf < 4; nf++)
#pragma unroll
            for (int kd = 0; kd < 2; kd++)
              sc[nf] = __builtin_amdgcn_mfma_f32_16x16x32_bf16(
                  kfr[nf][kd], qf[c][kd], sc[nf], 0, 0, 0);
          __builtin_amdgcn_s_setprio(0);

          if (kst + 63 > rowb + c * 16) {   // tile can cross diagonal: mask
#pragma unroll
            for (int nf = 0; nf < 4; nf++)
#pragma unroll
              for (int j = 0; j < 4; j++)
                if (kst + nf * 16 + g * 4 + j > qg) sc[nf][j] = -1e30f;
          }

          // online softmax (exp2 domain), defer-max THR=12
          float pm = fmaxf(fmaxf(fmaxf(sc[0][0], sc[0][1]), fmaxf(sc[0][2], sc[0][3])),
                           fmaxf(fmaxf(sc[1][0], sc[1][1]), fmaxf(sc[1][2], sc[1][3])));
          pm = fmaxf(pm, fmaxf(fmaxf(fmaxf(sc[2][0], sc[2][1]), fmaxf(sc[2][2], sc[2][3])),
                               fmaxf(fmaxf(sc[3][0], sc[3][1]), fmaxf(sc[3][2], sc[3][3]))));
          pm = fmaxf(pm, __shfl_xor(pm, 16));   // row-max across g groups
          pm = fmaxf(pm, __shfl_xor(pm, 32));
          if (__any(pm > mrun[c] + 12.0f)) {
            float mnew = fmaxf(mrun[c], pm);
            float al = exp2f(mrun[c] - mnew);
            mrun[c] = mnew;
            lrun[c] *= al;
#pragma unroll
            for (int d = 0; d < 4; d++) acc[c][d] *= al;
          }
          float ls = 0.f;
#pragma unroll
          for (int nf = 0; nf < 4; nf++) {
            float p0 = exp2f(sc[nf][0] - mrun[c]);
            float p1 = exp2f(sc[nf][1] - mrun[c]);
            float p2 = exp2f(sc[nf][2] - mrun[c]);
            float p3 = exp2f(sc[nf][3] - mrun[c]);
            ls += (p0 + p1) + (p2 + p3);
            uint2 u;
            u.x = cvtpk(p0, p1);
            u.y = cvtpk(p2, p3);
            *(uint2*)(void*)(Pw + r * 64 + ((nf * 16 + g * 4) ^ sw)) = u;
          }
          ls += __shfl_xor(ls, 16);
          ls += __shfl_xor(ls, 32);
          lrun[c] += ls;

          // PV swapped: O^T += V^T x P^T. P bounce wave-private; compiler
          // emits counted lgkmcnt for the ds_write -> ds_read dependency.
          bf16x8 pf[2];
          pf[0] = *(const bf16x8*)(const void*)(Pw + r * 64 + ((g * 8) ^ sw));
          pf[1] = *(const bf16x8*)(const void*)(Pw + r * 64 + ((32 + g * 8) ^ sw));
          __builtin_amdgcn_s_setprio(1);
#pragma unroll
          for (int d = 0; d < 4; d++)
#pragma unroll
            for (int ks = 0; ks < 2; ks++)
              acc[c][d] = __builtin_amdgcn_mfma_f32_16x16x32_bf16(
                  vfr[d][ks], pf[ks], acc[c][d], 0, 0, 0);
          __builtin_amdgcn_s_setprio(0);
        }
      }

      __builtin_amdgcn_sched_barrier(0);
      __builtin_amdgcn_s_barrier();   // all readers done before buffer reuse
    }

    // write z[qrow][h*64 + d*16 + g*4 + j], 2 col-tiles
#pragma unroll
    for (int c = 0; c < 2; c++) {
      float inv = 1.0f / lrun[c];
      long long qr = LL(b) * S_LEN + rowb + c * 16 + r;
#pragma unroll
      for (int d = 0; d < 4; d++) {
        uint2 u;
        u.x = cvtpk(acc[c][d][0] * inv, acc[c][d][1] * inv);
        u.y = cvtpk(acc[c][d][2] * inv, acc[c][d][3] * inv);
        *(uint2*)(void*)(zb + qr * DIM + h * HD + d * 16 + g * 4) = u;
      }
    }
  }
#undef STAGE
}

extern "C" void kernel_launch(void* const* d_in, const int* in_sizes, int n_in,
                              void* d_out, int out_size, void* d_ws, size_t ws_size,
                              hipStream_t stream) {
  const float* x  = (const float*)d_in[0];
  const float* Wq = (const float*)d_in[2];
  const float* Wk = (const float*)d_in[3];
  const float* Wv = (const float*)d_in[4];
  const float* Wo = (const float*)d_in[5];
  float* out = (float*)d_out;

  char* wsb = (char*)d_ws;
  size_t off = 0;
  auto alloc = [&](size_t bytes) {
    void* p = wsb + off;
    off += (bytes + 255) & ~(size_t)255;
    return p;
  };
  float* tab            = (float*)alloc(LL(S_LEN) * 32 * 2 * 4);
  unsigned short* xb    = (unsigned short*)alloc(LL(BS) * DIM * 2);
  unsigned short* wqkvt = (unsigned short*)alloc(LL(NQKV) * DIM * 2);
  unsigned short* wot   = (unsigned short*)alloc(LL(DIM) * DIM * 2);
  unsigned short* qbuf  = (unsigned short*)alloc(LL(BS) * DIM * 2);
  unsigned short* kbuf  = (unsigned short*)alloc(LL(BS) * (NKV * HD) * 2);
  unsigned short* vbuf  = (unsigned short*)alloc(LL(BS) * (NKV * HD) * 2);
  unsigned short* vtb   = (unsigned short*)alloc(LL(2 * NKV) * HD * S_LEN * 2);
  unsigned short* zb    = (unsigned short*)alloc(LL(BS) * DIM * 2);

  k_rope_tab<<<(S_LEN * 32 + 255) / 256, 256, 0, stream>>>(tab);
  k_cast4<<<(BS * DIM / 4 + 255) / 256, 256, 0, stream>>>(x, xb, BS * DIM / 4);
  k_tcast<<<dim3(DIM / 32, DIM / 32), dim3(32, 8), 0, stream>>>(Wq, wqkvt, DIM, DIM);
  k_tcast<<<dim3(512 / 32, DIM / 32), dim3(32, 8), 0, stream>>>(Wk, wqkvt + LL(2048) * DIM, DIM, 512);
  k_tcast<<<dim3(512 / 32, DIM / 32), dim3(32, 8), 0, stream>>>(Wv, wqkvt + LL(2560) * DIM, DIM, 512);
  k_tcast<<<dim3(DIM / 32, DIM / 32), dim3(32, 8), 0, stream>>>(Wo, wot, DIM, DIM);

  k_gemm<2><<<dim3(NQKV / 128, BS / 128), 256, 0, stream>>>(
      xb, wqkvt, nullptr, BS, NQKV, DIM, tab, qbuf, kbuf, vbuf);

  k_vtrans<<<dim3(S_LEN / 64, 2 * NKV), 256, 0, stream>>>(vbuf, vtb);

  k_attn<<<dim3(8, NH, 2), 256, 0, stream>>>(qbuf, kbuf, vtb, zb);

  k_gemm<0><<<dim3(DIM / 128, BS / 128), 256, 0, stream>>>(
      zb, wot, out, BS, DIM, DIM, nullptr, nullptr, nullptr, nullptr);
}

// Round 4
// 229.753 us; speedup vs baseline: 1.0434x; 1.0434x over previous
//
#include <hip/hip_runtime.h>
#include <hip/hip_bf16.h>

// GQA prefill: x@[Wq|Wk|Wv] (rope fused) -> causal GQA flash attention -> @Wo
// B=2 S=2048 D=2048 H=32 Hkv=8 hd=64 G=4. All GEMMs bf16-MFMA, fp32 accum.
// R4: 32x32-MFMA attention, bugfixed. Swapped QK^T (mfma(K,Q) 32x32x16):
// lane holds half a P-row; cross-half ops use __shfl_xor(.,32) (proven
// semantics) instead of permlane asm (R3's self-aliased swap caused lrun=0
// -> 1/0*0 = NaN). P stays in registers: cvt_pk + one shfl_xor per dword
// pair builds PV B-frags directly. No P LDS bounce.

#define S_LEN 2048
#define DIM   2048
#define NH    32
#define NKV   8
#define HD    64
#define BS    4096      // B*S rows
#define NQKV  3072      // 2048 q + 512 k + 512 v
#define LL(x) ((long long)(x))

typedef __bf16 bf16x8 __attribute__((ext_vector_type(8)));
typedef float  f32x4  __attribute__((ext_vector_type(4)));
typedef float  f32x16 __attribute__((ext_vector_type(16)));
typedef unsigned u32x4 __attribute__((ext_vector_type(4)));

__device__ __forceinline__ unsigned short bfb(float f) {
  __hip_bfloat16 h = __float2bfloat16(f);
  return *reinterpret_cast<unsigned short*>(&h);
}

__device__ __forceinline__ unsigned cvtpk(float lo, float hi) {
  unsigned u;
  asm("v_cvt_pk_bf16_f32 %0, %1, %2" : "=v"(u) : "v"(lo), "v"(hi));
  return u;
}

__device__ __forceinline__ void gload16(const void* g, void* l) {
  __builtin_amdgcn_global_load_lds(
      (const __attribute__((address_space(1))) void*)g,
      (__attribute__((address_space(3))) void*)l, 16, 0, 0);
}

// ---- RoPE cos/sin table: [2048][32][2] f32 (double trig for accuracy) ----
__global__ void k_rope_tab(float* __restrict__ tab) {
  int i = blockIdx.x * 256 + threadIdx.x;
  if (i >= S_LEN * 32) return;
  int s = i >> 5, f = i & 31;
  double inv = pow(500000.0, -2.0 * (double)f / 64.0);
  double fr = (double)s * inv;
  tab[2 * i]     = (float)cos(fr);
  tab[2 * i + 1] = (float)sin(fr);
}

// ---- fp32 -> bf16 cast, 4-wide ----
__global__ void k_cast4(const float* __restrict__ in, unsigned short* __restrict__ out, int n4) {
  int i = blockIdx.x * 256 + threadIdx.x;
  if (i >= n4) return;
  float4 v = ((const float4*)in)[i];
  ushort4 o;
  o.x = bfb(v.x); o.y = bfb(v.y); o.z = bfb(v.z); o.w = bfb(v.w);
  ((ushort4*)out)[i] = o;
}

// ---- transpose + cast: in[K][N] f32 -> out[N][K] bf16 ----
__global__ void k_tcast(const float* __restrict__ in, unsigned short* __restrict__ out,
                        int K, int N) {
  __shared__ float tile[32][33];
  int n0 = blockIdx.x * 32, k0 = blockIdx.y * 32;
  int tx = threadIdx.x, ty = threadIdx.y;  // 32x8
#pragma unroll
  for (int r = 0; r < 32; r += 8) tile[ty + r][tx] = in[LL(k0 + ty + r) * N + n0 + tx];
  __syncthreads();
#pragma unroll
  for (int r = 0; r < 32; r += 8) out[LL(n0 + ty + r) * K + k0 + tx] = bfb(tile[tx][ty + r]);
}

// ---- V transpose: vbuf[(b*S+s)][kvh*64+d] -> vt[(b*8+kvh)*64+d][s] (bf16) ----
__global__ void k_vtrans(const unsigned short* __restrict__ vbuf, unsigned short* __restrict__ vt) {
  __shared__ __align__(16) unsigned short tile[64][72];
  int s0 = blockIdx.x * 64;
  int bh = blockIdx.y;             // b*8 + kvh
  int b = bh >> 3, kvh = bh & 7;
  int t = threadIdx.x;
#pragma unroll
  for (int c = t; c < 512; c += 256) {
    int s = c >> 3, seg = c & 7;
    *(uint4*)&tile[s][seg * 8] =
        *(const uint4*)(vbuf + LL(b * S_LEN + s0 + s) * (NKV * HD) + kvh * HD + seg * 8);
  }
  __syncthreads();
#pragma unroll
  for (int c = t; c < 512; c += 256) {
    int d = c >> 3, sseg = c & 7;
    ushort4 x0, x1;
    unsigned short* xp = (unsigned short*)&x0;
#pragma unroll
    for (int j = 0; j < 4; j++) xp[j] = tile[sseg * 8 + j][d];
    unsigned short* yp = (unsigned short*)&x1;
#pragma unroll
    for (int j = 0; j < 4; j++) yp[j] = tile[sseg * 8 + 4 + j][d];
    uint4 o;
    o.x = ((unsigned*)&x0)[0]; o.y = ((unsigned*)&x0)[1];
    o.z = ((unsigned*)&x1)[0]; o.w = ((unsigned*)&x1)[1];
    *(uint4*)(vt + (LL(bh) * HD + d) * S_LEN + s0 + sseg * 8) = o;
  }
}

// ---- bf16 MFMA GEMM: C[M][N] = A[M][K] * Bt[N][K]^T  (m97 structure + T1 swizzle) ----
// MODE 0: fp32 out. MODE 2: fused QKV epilogue (rope on q/k cols, split outputs).
template <int MODE>
__global__ __launch_bounds__(256, 2) void k_gemm(
    const unsigned short* __restrict__ A, const unsigned short* __restrict__ Bt,
    void* __restrict__ Cout, int M, int N, int K,
    const float* __restrict__ tab, unsigned short* __restrict__ qbuf,
    unsigned short* __restrict__ kbuf, unsigned short* __restrict__ vbuf) {
  __shared__ __align__(16) unsigned short As[128 * 32];
  __shared__ __align__(16) unsigned short Bs[128 * 32];
  int t = threadIdx.x;
  int lane = t & 63, w = t >> 6;
  int wr = w >> 1, wc = w & 1;
  int g = lane >> 4, r = lane & 15;
  // XCD-aware bijective swizzle (nwg % 8 == 0 for all our launches)
  int gx = gridDim.x;
  int nwg = gx * gridDim.y;
  int lin = blockIdx.y * gx + blockIdx.x;
  int cpx = nwg >> 3;
  int swz = (lin & 7) * cpx + (lin >> 3);
  int bx = swz % gx, by = swz / gx;
  long long rowBase = LL(by) * 128;
  long long colBase = LL(bx) * 128;

  f32x4 acc[4][4] = {};

  int c0 = t, c1 = t + 256;
  const unsigned short* ag0 = A + (rowBase + (c0 >> 2)) * K + (c0 & 3) * 8;
  const unsigned short* ag1 = A + (rowBase + (c1 >> 2)) * K + (c1 & 3) * 8;
  const unsigned short* bg0 = Bt + (colBase + (c0 >> 2)) * K + (c0 & 3) * 8;
  const unsigned short* bg1 = Bt + (colBase + (c1 >> 2)) * K + (c1 & 3) * 8;
  char* lA0 = (char*)As + c0 * 16; char* lA1 = (char*)As + c1 * 16;
  char* lB0 = (char*)Bs + c0 * 16; char* lB1 = (char*)Bs + c1 * 16;

  for (int kt = 0; kt < K; kt += 32) {
    __syncthreads();
    gload16(ag0 + kt, lA0);
    gload16(ag1 + kt, lA1);
    gload16(bg0 + kt, lB0);
    gload16(bg1 + kt, lB1);
    __syncthreads();

    bf16x8 af[4], bfr[4];
#pragma unroll
    for (int m = 0; m < 4; m++)
      af[m] = *(const bf16x8*)(const void*)(As + (wr * 64 + m * 16 + r) * 32 + g * 8);
#pragma unroll
    for (int n = 0; n < 4; n++)
      bfr[n] = *(const bf16x8*)(const void*)(Bs + (wc * 64 + n * 16 + r) * 32 + g * 8);
#pragma unroll
    for (int m = 0; m < 4; m++)
#pragma unroll
      for (int n = 0; n < 4; n++)
        acc[m][n] = __builtin_amdgcn_mfma_f32_16x16x32_bf16(af[m], bfr[n], acc[m][n], 0, 0, 0);
  }

  if (MODE == 0) {
#pragma unroll
    for (int m = 0; m < 4; m++)
#pragma unroll
      for (int n = 0; n < 4; n++) {
        long long row0 = rowBase + wr * 64 + m * 16 + g * 4;
        long long col = colBase + wc * 64 + n * 16 + r;
#pragma unroll
        for (int j = 0; j < 4; j++)
          ((float*)Cout)[(row0 + j) * N + col] = acc[m][n][j];
      }
  } else {
    // fused QKV epilogue. cols: [0,2048) q (rope, *0.125*log2e), [2048,2560) k (rope),
    // [2560,3072) v (plain). rope: partner value in lane r^1.
#pragma unroll
    for (int n = 0; n < 4; n++) {
      int gc0 = (int)colBase + wc * 64 + n * 16;  // uniform 16-col block
      int gc = gc0 + r;
      unsigned short* dst; int dcol, dstride; float scale; bool rope;
      if (gc0 < 2048)      { dst = qbuf; dcol = gc;        dstride = DIM; scale = 0.18033688f; rope = true; }
      else if (gc0 < 2560) { dst = kbuf; dcol = gc - 2048; dstride = 512; scale = 1.0f;        rope = true; }
      else                 { dst = vbuf; dcol = gc - 2560; dstride = 512; scale = 1.0f;        rope = false; }
      int f = (gc & 63) >> 1;
      float sgn = (gc & 1) ? 1.f : -1.f;
#pragma unroll
      for (int m = 0; m < 4; m++) {
        long long row0 = rowBase + wr * 64 + m * 16 + g * 4;
#pragma unroll
        for (int j = 0; j < 4; j++) {
          float v = acc[m][n][j];
          float o;
          if (rope) {
            float part = __shfl_xor(v, 1);
            int s = (int)((row0 + j) & (S_LEN - 1));
            float cc = tab[(s * 32 + f) * 2], ss = tab[(s * 32 + f) * 2 + 1];
            o = (v * cc + sgn * part * ss) * scale;
          } else o = v;
          dst[(row0 + j) * dstride + dcol] = bfb(o);
        }
      }
    }
  }
}

// ---- causal GQA flash attention, 32x32 MFMA, in-register softmax + P ----
// grid (8, H, B) decoded XCD-aware; block 256 (4 waves x 32 q-rows = 128-row
// supertile). Supertile pair (p, 15-p): 34 balanced KV-tile iterations.
// Swapped QK^T (mfma(K,Q) 32x32x16): lane (l31,hi) holds keys
// {(q&3)+8*(q>>2)+4*hi} of q-row l31; partner lane l^32 holds the other half.
// Cross-half: __shfl_xor(.,32). 32KB LDS. Dbuf K/V via global_load_lds,
// counted vmcnt(4), 2 barriers/tile.
__global__ __launch_bounds__(256, 2) void k_attn(
    const unsigned short* __restrict__ qb, const unsigned short* __restrict__ kb,
    const unsigned short* __restrict__ vt, unsigned short* __restrict__ zb) {
  // XCD-aware decode: kvh == (linear id & 7) == XCD -> each XCD's blocks
  // share one (kvh) K/V working set (~1MB, L2-resident).
  int lin = blockIdx.x + 8 * (blockIdx.y + 32 * blockIdx.z);  // 0..511
  int kvh = lin & 7;
  int idx = lin >> 3;          // 0..63
  int b = idx >> 5;            // 0..1
  int j = idx & 31;            // 0..31
  int h = kvh * 4 + (j & 3);
  int pair = j >> 2;           // 0..7
  int bh = b * NKV + kvh;

  int t = threadIdx.x, lane = t & 63, w = t >> 6;
  int l31 = lane & 31, hi = lane >> 5;
  int sw = (l31 & 7) * 8;      // ushort-index XOR swizzle (16B granule, 128B rows)

  __shared__ __align__(16) unsigned short Ks[2][64 * 64];  // [key][d]  swizzled
  __shared__ __align__(16) unsigned short Vs[2][64 * 64];  // [d][key]  swizzled

  // staging chunks: c -> row=c>>3, slot=c&7; source slot ^= row&7
  int c0 = t, c1 = t + 256;
  const unsigned short* kg0 = kb + LL(b) * S_LEN * 512 + (c0 >> 3) * 512 + kvh * HD
                                 + (((c0 & 7) ^ ((c0 >> 3) & 7)) * 8);
  const unsigned short* kg1 = kb + LL(b) * S_LEN * 512 + (c1 >> 3) * 512 + kvh * HD
                                 + (((c1 & 7) ^ ((c1 >> 3) & 7)) * 8);
  const unsigned short* vg0 = vt + (LL(bh) * HD + (c0 >> 3)) * S_LEN
                                 + (((c0 & 7) ^ ((c0 >> 3) & 7)) * 8);
  const unsigned short* vg1 = vt + (LL(bh) * HD + (c1 >> 3)) * S_LEN
                                 + (((c1 & 7) ^ ((c1 >> 3) & 7)) * 8);

#define STAGE(bufi, kst_)                                              \
  {                                                                    \
    gload16(kg0 + LL(kst_) * 512, (char*)Ks[bufi] + c0 * 16);          \
    gload16(kg1 + LL(kst_) * 512, (char*)Ks[bufi] + c1 * 16);          \
    gload16(vg0 + (kst_), (char*)Vs[bufi] + c0 * 16);                  \
    gload16(vg1 + (kst_), (char*)Vs[bufi] + c1 * 16);                  \
  }

#pragma unroll 1
  for (int pass = 0; pass < 2; pass++) {
    int st = pass ? (15 - pair) : pair;   // supertile index (128 rows)
    int rowb = st * 128 + w * 32;         // wave's first q-row
    int qg = rowb + l31;                  // this lane's q-row
    long long qrow = LL(b) * S_LEN + qg;

    // Q fragments (pre-scaled by 0.125*log2e in GEMM epilogue):
    // qf[s] elem e = Q[qrow][s*16 + hi*8 + e]  (B-frag: col=l31, k=hi*8+e)
    bf16x8 qf[4];
#pragma unroll
    for (int s = 0; s < 4; s++)
      qf[s] = *(const bf16x8*)(const void*)(qb + qrow * DIM + h * HD + s * 16 + hi * 8);

    f32x16 acc0 = {}, acc1 = {};   // O^T[db*32 + crow][qrow], db=0,1
    float mrun = -1e30f, lrun = 0.f;

    int nt = 2 * st + 2;
    __syncthreads();          // prior pass's readers done; buffers free
    STAGE(0, 0);
    for (int tt = 0; tt < nt; tt++) {
      int kst = tt * 64;
      int cur = tt & 1;
      if (tt + 1 < nt) {
        STAGE(cur ^ 1, kst + 64);
        asm volatile("s_waitcnt vmcnt(4)" ::: "memory");  // tile tt landed
      } else {
        asm volatile("s_waitcnt vmcnt(0)" ::: "memory");
      }
      __builtin_amdgcn_s_barrier();
      __builtin_amdgcn_sched_barrier(0);

      // wave-uniform: does this tile intersect this wave's rows?
      if (kst <= rowb + 31) {
        const unsigned short* Kc = Ks[cur];
        const unsigned short* Vc = Vs[cur];

        // K A-frags: kf[kbi][s] elem e = K[kbi*32+l31][s*16 + hi*8 + e]
        bf16x8 kf[2][4];
#pragma unroll
        for (int kbi = 0; kbi < 2; kbi++)
#pragma unroll
          for (int s = 0; s < 4; s++)
            kf[kbi][s] = *(const bf16x8*)(const void*)(
                Kc + (kbi * 32 + l31) * 64 + ((s * 16 + hi * 8) ^ sw));

        // swapped QK^T: C[key][qrow]; col=l31 (qrow), key=(reg&3)+8*(reg>>2)+4*hi
        __builtin_amdgcn_s_setprio(1);
        f32x16 sc0 = {}, sc1 = {};
#pragma unroll
        for (int s = 0; s < 4; s++) {
          sc0 = __builtin_amdgcn_mfma_f32_32x32x16_bf16(kf[0][s], qf[s], sc0, 0, 0, 0);
          sc1 = __builtin_amdgcn_mfma_f32_32x32x16_bf16(kf[1][s], qf[s], sc1, 0, 0, 0);
        }
        __builtin_amdgcn_s_setprio(0);

        // V A-frags hoisted (no dep on P): vf[db*4+f] elem e =
        // V^T[db*32+l31][f*16 + hi*8 + e]
        bf16x8 vf[8];
#pragma unroll
        for (int db = 0; db < 2; db++)
#pragma unroll
          for (int f = 0; f < 4; f++)
            vf[db * 4 + f] = *(const bf16x8*)(const void*)(
                Vc + (db * 32 + l31) * 64 + ((f * 16 + hi * 8) ^ sw));

        if (kst + 63 > rowb) {   // diagonal region: causal mask
#pragma unroll
          for (int q = 0; q < 16; q++) {
            int kl = (q & 3) + 8 * (q >> 2) + 4 * hi;
            if (kst + kl > qg) sc0[q] = -1e30f;
            if (kst + 32 + kl > qg) sc1[q] = -1e30f;
          }
        }

        // online softmax (exp2 domain), defer-max THR=12.
        float pm = -1e30f;
#pragma unroll
        for (int q = 0; q < 16; q++) {
          pm = fmaxf(pm, sc0[q]);
          pm = fmaxf(pm, sc1[q]);
        }
        pm = fmaxf(pm, __shfl_xor(pm, 32));   // full row max (both halves)
        if (__any(pm > mrun + 12.0f)) {
          float mnew = fmaxf(mrun, pm);
          float al = exp2f(mrun - mnew);
          mrun = mnew;
          lrun *= al;
          acc0 *= al;
          acc1 *= al;
        }
        f32x16 pv0, pv1;
        float ls = 0.f;
#pragma unroll
        for (int q = 0; q < 16; q++) {
          pv0[q] = exp2f(sc0[q] - mrun);
          pv1[q] = exp2f(sc1[q] - mrun);
          ls += pv0[q] + pv1[q];
        }
        lrun += ls + __shfl_xor(ls, 32);      // full row sum

        // P -> PV B-frags in registers. Frag f needs elem e =
        // P[qrow][f*16 + hi*8 + e]. Own lane holds keys {0..3,8..11}+4*hi
        // of each 16-key group (q = qbase..qbase+7, qbase=(f&1)*8).
        // One shfl_xor(.,32) per dword pair brings the partner half.
        bf16x8 pfr[4];
#pragma unroll
        for (int f = 0; f < 4; f++) {
          int qb_ = (f & 1) * 8;
          float e0, e1, e2, e3, e4, e5, e6, e7;
          if (f < 2) {
            e0 = pv0[qb_ + 0]; e1 = pv0[qb_ + 1]; e2 = pv0[qb_ + 2]; e3 = pv0[qb_ + 3];
            e4 = pv0[qb_ + 4]; e5 = pv0[qb_ + 5]; e6 = pv0[qb_ + 6]; e7 = pv0[qb_ + 7];
          } else {
            e0 = pv1[qb_ + 0]; e1 = pv1[qb_ + 1]; e2 = pv1[qb_ + 2]; e3 = pv1[qb_ + 3];
            e4 = pv1[qb_ + 4]; e5 = pv1[qb_ + 5]; e6 = pv1[qb_ + 6]; e7 = pv1[qb_ + 7];
          }
          unsigned a0 = cvtpk(e0, e1), a1 = cvtpk(e2, e3);   // keys +0..3 (own set)
          unsigned b0 = cvtpk(e4, e5), b1 = cvtpk(e6, e7);   // keys +8..11 (own set)
          // hi=0 needs partner a0/a1 (keys 4..7); hi=1 needs partner b0/b1
          // (keys 8..11). Contribute what the partner needs, receive theirs.
          unsigned y0 = __shfl_xor(hi ? a0 : b0, 32);
          unsigned y1 = __shfl_xor(hi ? a1 : b1, 32);
          u32x4 uu;
          uu[0] = hi ? y0 : a0;   // keys f*16 + hi*8 + {0,1}
          uu[1] = hi ? y1 : a1;   //                  + {2,3}
          uu[2] = hi ? b0 : y0;   //                  + {4,5}
          uu[3] = hi ? b1 : y1;   //                  + {6,7}
          pfr[f] = *(bf16x8*)&uu;
        }

        // PV swapped: O^T += V^T x P^T
        __builtin_amdgcn_s_setprio(1);
#pragma unroll
        for (int f = 0; f < 4; f++) {
          acc0 = __builtin_amdgcn_mfma_f32_32x32x16_bf16(vf[f],     pfr[f], acc0, 0, 0, 0);
          acc1 = __builtin_amdgcn_mfma_f32_32x32x16_bf16(vf[4 + f], pfr[f], acc1, 0, 0, 0);
        }
        __builtin_amdgcn_s_setprio(0);
      }

      __builtin_amdgcn_sched_barrier(0);
      __builtin_amdgcn_s_barrier();   // all readers done before buffer reuse
    }

    // write z[qrow][h*64 + d], d = db*32 + 8*q4 + 4*hi + (0..3)
    float invl = 1.0f / lrun;
#pragma unroll
    for (int q4 = 0; q4 < 4; q4++) {
      uint2 u;
      u.x = cvtpk(acc0[q4 * 4 + 0] * invl, acc0[q4 * 4 + 1] * invl);
      u.y = cvtpk(acc0[q4 * 4 + 2] * invl, acc0[q4 * 4 + 3] * invl);
      *(uint2*)(void*)(zb + qrow * DIM + h * HD + 8 * q4 + 4 * hi) = u;
      uint2 v;
      v.x = cvtpk(acc1[q4 * 4 + 0] * invl, acc1[q4 * 4 + 1] * invl);
      v.y = cvtpk(acc1[q4 * 4 + 2] * invl, acc1[q4 * 4 + 3] * invl);
      *(uint2*)(void*)(zb + qrow * DIM + h * HD + 32 + 8 * q4 + 4 * hi) = v;
    }
  }
#undef STAGE
}

extern "C" void kernel_launch(void* const* d_in, const int* in_sizes, int n_in,
                              void* d_out, int out_size, void* d_ws, size_t ws_size,
                              hipStream_t stream) {
  const float* x  = (const float*)d_in[0];
  const float* Wq = (const float*)d_in[2];
  const float* Wk = (const float*)d_in[3];
  const float* Wv = (const float*)d_in[4];
  const float* Wo = (const float*)d_in[5];
  float* out = (float*)d_out;

  char* wsb = (char*)d_ws;
  size_t off = 0;
  auto alloc = [&](size_t bytes) {
    void* p = wsb + off;
    off += (bytes + 255) & ~(size_t)255;
    return p;
  };
  float* tab            = (float*)alloc(LL(S_LEN) * 32 * 2 * 4);
  unsigned short* xb    = (unsigned short*)alloc(LL(BS) * DIM * 2);
  unsigned short* wqkvt = (unsigned short*)alloc(LL(NQKV) * DIM * 2);
  unsigned short* wot   = (unsigned short*)alloc(LL(DIM) * DIM * 2);
  unsigned short* qbuf  = (unsigned short*)alloc(LL(BS) * DIM * 2);
  unsigned short* kbuf  = (unsigned short*)alloc(LL(BS) * (NKV * HD) * 2);
  unsigned short* vbuf  = (unsigned short*)alloc(LL(BS) * (NKV * HD) * 2);
  unsigned short* vtb   = (unsigned short*)alloc(LL(2 * NKV) * HD * S_LEN * 2);
  unsigned short* zb    = (unsigned short*)alloc(LL(BS) * DIM * 2);

  k_rope_tab<<<(S_LEN * 32 + 255) / 256, 256, 0, stream>>>(tab);
  k_cast4<<<(BS * DIM / 4 + 255) / 256, 256, 0, stream>>>(x, xb, BS * DIM / 4);
  k_tcast<<<dim3(DIM / 32, DIM / 32), dim3(32, 8), 0, stream>>>(Wq, wqkvt, DIM, DIM);
  k_tcast<<<dim3(512 / 32, DIM / 32), dim3(32, 8), 0, stream>>>(Wk, wqkvt + LL(2048) * DIM, DIM, 512);
  k_tcast<<<dim3(512 / 32, DIM / 32), dim3(32, 8), 0, stream>>>(Wv, wqkvt + LL(2560) * DIM, DIM, 512);
  k_tcast<<<dim3(DIM / 32, DIM / 32), dim3(32, 8), 0, stream>>>(Wo, wot, DIM, DIM);

  k_gemm<2><<<dim3(NQKV / 128, BS / 128), 256, 0, stream>>>(
      xb, wqkvt, nullptr, BS, NQKV, DIM, tab, qbuf, kbuf, vbuf);

  k_vtrans<<<dim3(S_LEN / 64, 2 * NKV), 256, 0, stream>>>(vbuf, vtb);

  k_attn<<<dim3(8, NH, 2), 256, 0, stream>>>(qbuf, kbuf, vtb, zb);

  k_gemm<0><<<dim3(DIM / 128, BS / 128), 256, 0, stream>>>(
      zb, wot, out, BS, DIM, DIM, nullptr, nullptr, nullptr, nullptr);
}